// Round 5
// baseline (916.131 us; speedup 1.0000x reference)
//
#include <hip/hip_runtime.h>
#include <math.h>

#define T_LEN   1024
#define S_SEAS  168
#define H_SZ    128
#define G_SZ    512   // 4*H
#define WIN_SZ  168
#define OUT_SZ  24
#define N_WIN   833
#define BB      16
#define NBLK    ((N_WIN + BB - 1) / BB)   // 53
#define NPAD    (NBLK * BB)               // 848

typedef __attribute__((ext_vector_type(8))) __bf16 bf16x8;
typedef __attribute__((ext_vector_type(4))) float  f32x4;

__device__ __forceinline__ float fsig(float x) {
    return __fdividef(1.0f, 1.0f + __expf(-x));
}
__device__ __forceinline__ float ftanh(float x) {
    return 1.0f - __fdividef(2.0f, __expf(2.0f * x) + 1.0f);
}

// LDS h-tile addressing: pitch 256B (128 bf16), XOR swizzle byte^=(row&7)<<4
// (m214 recipe). Verified rounds 2-4 (absmax 0.002).
__device__ __forceinline__ int hswz(int row, int colByte) {
    return row * 256 + (colByte ^ ((row & 7) << 4));
}

// ---------------------------------------------------------------------------
// Phase A: Holt-Winters ES scan (serial, software-pipelined).
// ---------------------------------------------------------------------------
__global__ void es_scan_kernel(const float* __restrict__ x,
                               const float* __restrict__ lvl_raw,
                               const float* __restrict__ seas_raw,
                               const float* __restrict__ seas_params,
                               float* __restrict__ levels,
                               float* __restrict__ wsv) {
    __shared__ float xl[T_LEN];
    __shared__ float buf[S_SEAS];
    const int t = threadIdx.x;
    for (int i = t; i < T_LEN; i += 256) xl[i] = x[i];
    for (int i = t; i < S_SEAS; i += 256) {
        const float w = expf(seas_params[i]);
        buf[i] = w;
        wsv[i] = w;
    }
    __syncthreads();
    if (t == 0) {
        const float a  = 1.0f / (1.0f + expf(-lvl_raw[0]));
        const float g  = 1.0f / (1.0f + expf(-seas_raw[0]));
        const float ca = 1.0f - a, cg = 1.0f - g;
        float level = __fdividef(xl[0], buf[0]);
        levels[0] = level;
        wsv[S_SEAS] = buf[0];   // ws_full[168] = w_init[0]

        float wq[8], tq[8];
#pragma unroll
        for (int k = 0; k < 8; ++k) {
            const int i = 1 + k;
            const float w = buf[i % S_SEAS];
            wq[k] = w;
            tq[k] = __fdividef(a * xl[i], w);
        }
        for (int i = 1; i < T_LEN; i += 8) {
#pragma unroll
            for (int s = 0; s < 8; ++s) {
                const int ii = i + s;
                if (ii >= T_LEN) break;
                const float w  = wq[s];
                const float nl = tq[s] + ca * level;      // critical chain: 1 FMA
                const float nw = cg * w + __fdividef(g * xl[ii], nl);
                levels[ii] = nl;
                buf[ii % S_SEAS] = nw;
                if (ii + S_SEAS < T_LEN) wsv[ii + S_SEAS] = nw;
                level = nl;
                const int i8 = ii + 8;
                if (i8 < T_LEN) {
                    const float w8 = buf[i8 % S_SEAS];
                    wq[s] = w8;
                    tq[s] = __fdividef(a * xl[i8], w8);
                }
            }
        }
    }
}

// ---------------------------------------------------------------------------
// Phase B: deseasonalized log inputs (time-major sq_inT [168][833]) + labels
// (directly into d_out) + level_var_loss scalar.
// ---------------------------------------------------------------------------
__global__ __launch_bounds__(256) void window_kernel(
    const float* __restrict__ x,
    const float* __restrict__ levels,
    const float* __restrict__ wsv,
    const float* __restrict__ noise_in,
    const float* __restrict__ noise_lab,
    float* __restrict__ sqT,
    float* __restrict__ outbuf) {
    const int p = blockIdx.x;   // 0..167: window pos; 168..191: label pos
    for (int nn = threadIdx.x; nn < N_WIN; nn += 256) {
        const float lev = levels[nn + WIN_SZ];
        if (p < WIN_SZ) {
            const int tt = nn + p;
            sqT[p * N_WIN + nn] =
                logf(x[tt] / (lev * wsv[tt])) + noise_in[nn * WIN_SZ + p];
        } else {
            const int o = p - WIN_SZ;
            const int tt = nn + WIN_SZ + o;
            outbuf[N_WIN * OUT_SZ + nn * OUT_SZ + o] =
                logf(x[tt] / (lev * wsv[tt])) + noise_lab[nn * OUT_SZ + o];
        }
    }
    if (blockIdx.x == 0 && threadIdx.x == 0)
        outbuf[2 * N_WIN * OUT_SZ] = 0.0f;   // level_var_loss
}

// ---------------------------------------------------------------------------
// Weight prep: pack Wh0 / [Wx1;Wh1] into per-lane bf16 MFMA B-fragments.
// B-frag layout (m92/m97): lane l holds col n=(l&15), 8 contiguous k at
// (l>>4)*8. Fragment f for wave w, gate ns, K-tile kt at pw[f*64+l].
// ---------------------------------------------------------------------------
__global__ __launch_bounds__(256) void prep_weights(
    const float* __restrict__ Wh0,
    const float* __restrict__ Wx1,
    const float* __restrict__ Wh1,
    const float* __restrict__ tanhW,
    uint4* __restrict__ pw0,
    uint4* __restrict__ pw1,
    float* __restrict__ tanhWT) {
    const int idx = blockIdx.x * 256 + threadIdx.x;
    auto bfr = [](float f) -> unsigned int {   // fp32 -> bf16 (RNE)
        union { float f; unsigned int u; } v; v.f = f;
        return ((v.u + 0x7FFFu + ((v.u >> 16) & 1u)) >> 16) & 0xFFFFu;
    };
    if (idx < 8192) {                       // pw0: Wh0, 128 frags (8w x 4ns x 4kt)
        const int l = idx & 63, f = idx >> 6;
        const int kt = f & 3, ns = (f >> 2) & 3, w = f >> 4;
        const int g = ns * 128 + w * 16 + (l & 15);
        const int kb = kt * 32 + (l >> 4) * 8;
        const float* s = Wh0 + g * H_SZ + kb;
        uint4 o;
        unsigned int* po = &o.x;
        for (int p = 0; p < 4; ++p) po[p] = bfr(s[2 * p]) | (bfr(s[2 * p + 1]) << 16);
        pw0[idx] = o;
    } else if (idx < 8192 + 16384) {        // pw1: [Wx1 (kt<4); Wh1 (kt>=4)], 256 frags
        const int j = idx - 8192;
        const int l = j & 63, f = j >> 6;
        const int kt = f & 7, ns = (f >> 3) & 3, w = f >> 5;
        const int g = ns * 128 + w * 16 + (l & 15);
        const float* srcm = (kt < 4) ? Wx1 : Wh1;
        const int kb = (kt & 3) * 32 + (l >> 4) * 8;
        const float* s = srcm + g * H_SZ + kb;
        uint4 o;
        unsigned int* po = &o.x;
        for (int p = 0; p < 4; ++p) po[p] = bfr(s[2 * p]) | (bfr(s[2 * p + 1]) << 16);
        pw1[j] = o;
    } else if (idx < 8192 + 16384 + 16384) {  // tanh_W transpose (fp32)
        const int j = idx - 8192 - 16384;
        const int m = j >> 7, k = j & 127;
        tanhWT[k * H_SZ + m] = tanhW[j];
    }
}

// ---------------------------------------------------------------------------
// Phase C0: layer-0 LSTM. Wh0 B-frags LDS-resident (128KB), re-read per step
// via conflict-free ds_read_b128. Per-thread state: c0 (4 regs) only.
// ---------------------------------------------------------------------------
__global__ __launch_bounds__(512) void l0_kernel(
    const float* __restrict__ sqT,
    const float* __restrict__ Wx0,
    const float* __restrict__ b0v,
    const uint4* __restrict__ pw0,
    __bf16* __restrict__ hs0) {
    __shared__ uint4  wls[128 * 64];       // Wh0 frags, 128KB
    __shared__ __bf16 h0s[2][16 * 128];    // 8KB, swizzled, pitch 256B
    __shared__ float  xls[WIN_SZ][16];     // 10.75KB

    const int tid  = threadIdx.x;
    const int w    = tid >> 6;
    const int lane = tid & 63;
    const int cc   = lane & 15;
    const int kl   = lane >> 4;
    const int base = blockIdx.x * BB;

    for (int i = tid; i < 128 * 64; i += 512) wls[i] = pw0[i];
    for (int i = tid; i < WIN_SZ * BB; i += 512) {
        const int t = i >> 4, m = i & 15;
        const int nn = base + m;
        xls[t][m] = (nn < N_WIN) ? sqT[t * N_WIN + nn] : 0.0f;
    }
    for (int i = tid; i < 2 * 16 * 128; i += 512) (&h0s[0][0])[i] = (__bf16)0.0f;

    float b0r[4], wx0r[4];
#pragma unroll
    for (int ns = 0; ns < 4; ++ns) {
        const int g = ns * 128 + w * 16 + cc;
        b0r[ns]  = b0v[g];
        wx0r[ns] = Wx0[g];
    }
    float c0r[4] = {0.f, 0.f, 0.f, 0.f};
    __syncthreads();

    // per-lane B-frag base in LDS: frag (w,ns,kt) at +(ns*4+kt)*64 elements
    const bf16x8* const wf = (const bf16x8*)&wls[(w * 16) * 64 + lane];
    char* const hb0 = (char*)&h0s[0][0];

    for (int t = 0; t < WIN_SZ; ++t) {
        asm volatile("" ::: "memory");     // pin all operand loads inside the step
        const int rb = t & 1, wb = rb ^ 1;
        const float4 xt = *(const float4*)&xls[t][kl * 4];
        const float xa[4] = {xt.x, xt.y, xt.z, xt.w};
        f32x4 acc0, acc1, acc2, acc3;
#pragma unroll
        for (int r = 0; r < 4; ++r) {
            acc0[r] = b0r[0] + wx0r[0] * xa[r];
            acc1[r] = b0r[1] + wx0r[1] * xa[r];
            acc2[r] = b0r[2] + wx0r[2] * xa[r];
            acc3[r] = b0r[3] + wx0r[3] * xa[r];
        }
#pragma unroll
        for (int kt = 0; kt < 4; ++kt) {
            const bf16x8 a = *(const bf16x8*)(hb0 + rb * 4096 + hswz(cc, kt * 64 + kl * 16));
            acc0 = __builtin_amdgcn_mfma_f32_16x16x32_bf16(a, wf[(0 * 4 + kt) * 64], acc0, 0, 0, 0);
            acc1 = __builtin_amdgcn_mfma_f32_16x16x32_bf16(a, wf[(1 * 4 + kt) * 64], acc1, 0, 0, 0);
            acc2 = __builtin_amdgcn_mfma_f32_16x16x32_bf16(a, wf[(2 * 4 + kt) * 64], acc2, 0, 0, 0);
            acc3 = __builtin_amdgcn_mfma_f32_16x16x32_bf16(a, wf[(3 * 4 + kt) * 64], acc3, 0, 0, 0);
        }
#pragma unroll
        for (int r = 0; r < 4; ++r) {
            const float ig = fsig(acc0[r]);
            const float fg = fsig(acc1[r]);
            const float gg = ftanh(acc2[r]);
            const float og = fsig(acc3[r]);
            const float c  = fg * c0r[r] + ig * gg;
            c0r[r] = c;
            const __bf16 hb = (__bf16)(og * ftanh(c));
            const int row = kl * 4 + r;
            *(__bf16*)(hb0 + wb * 4096 + hswz(row, (w * 16 + cc) * 2)) = hb;
            hs0[t * (NPAD * H_SZ) + (base + row) * H_SZ + w * 16 + cc] = hb;
        }
        __syncthreads();
    }
}

// ---------------------------------------------------------------------------
// Phase C1: layer-1 LSTM. Wh1 B-frags LDS-resident (128KB); Wx1 B-frags read
// per step from global (L2-resident, fixed per-lane addresses); A-operand of
// the Wx1 term streams from hs0 with named-register 1-step prefetch.
// ---------------------------------------------------------------------------
__global__ __launch_bounds__(512) void l1_kernel(
    const __bf16* __restrict__ hs0,
    const float* __restrict__ b1v,
    const uint4* __restrict__ pw1,
    float* __restrict__ hfin) {
    __shared__ uint4  wls[128 * 64];       // Wh1 frags, 128KB
    __shared__ __bf16 h1s[2][16 * 128];    // 8KB, swizzled

    const int tid  = threadIdx.x;
    const int w    = tid >> 6;
    const int lane = tid & 63;
    const int cc   = lane & 15;
    const int kl   = lane >> 4;
    const int base = blockIdx.x * BB;

    // stage Wh1 (pw1 kt>=4 region) into compact (w,ns,kt) LDS frags
    for (int i = tid; i < 128 * 64; i += 512) {
        const int l = i & 63, f = i >> 6;      // f = (w*4+ns)*4 + kt
        const int kt = f & 3, nsw = f >> 2;    // nsw = w*4+ns
        wls[i] = pw1[(nsw * 8 + kt + 4) * 64 + l];
    }
    for (int i = tid; i < 2 * 16 * 128; i += 512) (&h1s[0][0])[i] = (__bf16)0.0f;

    float b1r[4];
#pragma unroll
    for (int ns = 0; ns < 4; ++ns) b1r[ns] = b1v[ns * 128 + w * 16 + cc];
    float c1r[4] = {0.f, 0.f, 0.f, 0.f};

    // Wx1 global frag accessor (kt<4 region of pw1); addresses fixed per lane
    const bf16x8* const gx = (const bf16x8*)pw1;
#define GX(ns, kt) gx[(((w * 4 + (ns)) * 8 + (kt)) * 64) + lane]

    // A-frag prefetch for t=0 (named regs)
    const int arow = (base + cc) * H_SZ + kl * 8;
    bf16x8 f0 = *(const bf16x8*)&hs0[arow + 0];
    bf16x8 f1 = *(const bf16x8*)&hs0[arow + 32];
    bf16x8 f2 = *(const bf16x8*)&hs0[arow + 64];
    bf16x8 f3 = *(const bf16x8*)&hs0[arow + 96];
    __syncthreads();

    const bf16x8* const wf = (const bf16x8*)&wls[(w * 16) * 64 + lane];
    char* const hb1 = (char*)&h1s[0][0];

    for (int t = 0; t < WIN_SZ; ++t) {
        asm volatile("" ::: "memory");     // pin operand loads inside the step
        const int rb = t & 1, wb = rb ^ 1;

        bf16x8 g0 = f0, g1 = f1, g2 = f2, g3 = f3;
        if (t < WIN_SZ - 1) {
            const __bf16* p = hs0 + (t + 1) * (NPAD * H_SZ) + arow;
            g0 = *(const bf16x8*)(p);
            g1 = *(const bf16x8*)(p + 32);
            g2 = *(const bf16x8*)(p + 64);
            g3 = *(const bf16x8*)(p + 96);
        }

        f32x4 acc0 = {b1r[0], b1r[0], b1r[0], b1r[0]};
        f32x4 acc1 = {b1r[1], b1r[1], b1r[1], b1r[1]};
        f32x4 acc2 = {b1r[2], b1r[2], b1r[2], b1r[2]};
        f32x4 acc3 = {b1r[3], b1r[3], b1r[3], b1r[3]};

        // Wx1 term: A = prefetched hs0 frags, B from global (L2-hot)
        acc0 = __builtin_amdgcn_mfma_f32_16x16x32_bf16(f0, GX(0, 0), acc0, 0, 0, 0);
        acc1 = __builtin_amdgcn_mfma_f32_16x16x32_bf16(f0, GX(1, 0), acc1, 0, 0, 0);
        acc2 = __builtin_amdgcn_mfma_f32_16x16x32_bf16(f0, GX(2, 0), acc2, 0, 0, 0);
        acc3 = __builtin_amdgcn_mfma_f32_16x16x32_bf16(f0, GX(3, 0), acc3, 0, 0, 0);
        acc0 = __builtin_amdgcn_mfma_f32_16x16x32_bf16(f1, GX(0, 1), acc0, 0, 0, 0);
        acc1 = __builtin_amdgcn_mfma_f32_16x16x32_bf16(f1, GX(1, 1), acc1, 0, 0, 0);
        acc2 = __builtin_amdgcn_mfma_f32_16x16x32_bf16(f1, GX(2, 1), acc2, 0, 0, 0);
        acc3 = __builtin_amdgcn_mfma_f32_16x16x32_bf16(f1, GX(3, 1), acc3, 0, 0, 0);
        acc0 = __builtin_amdgcn_mfma_f32_16x16x32_bf16(f2, GX(0, 2), acc0, 0, 0, 0);
        acc1 = __builtin_amdgcn_mfma_f32_16x16x32_bf16(f2, GX(1, 2), acc1, 0, 0, 0);
        acc2 = __builtin_amdgcn_mfma_f32_16x16x32_bf16(f2, GX(2, 2), acc2, 0, 0, 0);
        acc3 = __builtin_amdgcn_mfma_f32_16x16x32_bf16(f2, GX(3, 2), acc3, 0, 0, 0);
        acc0 = __builtin_amdgcn_mfma_f32_16x16x32_bf16(f3, GX(0, 3), acc0, 0, 0, 0);
        acc1 = __builtin_amdgcn_mfma_f32_16x16x32_bf16(f3, GX(1, 3), acc1, 0, 0, 0);
        acc2 = __builtin_amdgcn_mfma_f32_16x16x32_bf16(f3, GX(2, 3), acc2, 0, 0, 0);
        acc3 = __builtin_amdgcn_mfma_f32_16x16x32_bf16(f3, GX(3, 3), acc3, 0, 0, 0);

        // Wh1 term: A = h1_prev from LDS, B from LDS
#pragma unroll
        for (int kt = 0; kt < 4; ++kt) {
            const bf16x8 a = *(const bf16x8*)(hb1 + rb * 4096 + hswz(cc, kt * 64 + kl * 16));
            acc0 = __builtin_amdgcn_mfma_f32_16x16x32_bf16(a, wf[(0 * 4 + kt) * 64], acc0, 0, 0, 0);
            acc1 = __builtin_amdgcn_mfma_f32_16x16x32_bf16(a, wf[(1 * 4 + kt) * 64], acc1, 0, 0, 0);
            acc2 = __builtin_amdgcn_mfma_f32_16x16x32_bf16(a, wf[(2 * 4 + kt) * 64], acc2, 0, 0, 0);
            acc3 = __builtin_amdgcn_mfma_f32_16x16x32_bf16(a, wf[(3 * 4 + kt) * 64], acc3, 0, 0, 0);
        }

#pragma unroll
        for (int r = 0; r < 4; ++r) {
            const float ig = fsig(acc0[r]);
            const float fg = fsig(acc1[r]);
            const float gg = ftanh(acc2[r]);
            const float og = fsig(acc3[r]);
            const float c  = fg * c1r[r] + ig * gg;
            c1r[r] = c;
            const float hv = og * ftanh(c);
            const int row = kl * 4 + r;
            if (t < WIN_SZ - 1) {
                *(__bf16*)(hb1 + wb * 4096 + hswz(row, (w * 16 + cc) * 2)) = (__bf16)hv;
            } else {
                const int nn = base + row;
                if (nn < N_WIN) hfin[nn * H_SZ + w * 16 + cc] = hv;
            }
        }
        __syncthreads();
        f0 = g0; f1 = g1; f2 = g2; f3 = g3;
    }
#undef GX
}

// ---------------------------------------------------------------------------
// Phase D: head — feat = tanh(h @ tanh_W^T + tanh_b); out = feat @ lin_W^T + lin_b
// ---------------------------------------------------------------------------
__global__ __launch_bounds__(128) void head_kernel(
    const float* __restrict__ hfin,
    const float* __restrict__ tanhWT,
    const float* __restrict__ tanhB,
    const float* __restrict__ linW,
    const float* __restrict__ linB,
    float* __restrict__ out) {
    __shared__ float hl[H_SZ];
    __shared__ float fl[H_SZ];
    const int nn = blockIdx.x;
    const int m = threadIdx.x;
    hl[m] = hfin[nn * H_SZ + m];
    __syncthreads();
    float acc = tanhB[m];
    for (int k = 0; k < H_SZ; ++k) acc += hl[k] * tanhWT[k * H_SZ + m];
    fl[m] = tanhf(acc);
    __syncthreads();
    if (m < OUT_SZ) {
        float a = linB[m];
        for (int k = 0; k < H_SZ; ++k) a += fl[k] * linW[m * H_SZ + k];
        out[nn * OUT_SZ + m] = a;
    }
}

// ---------------------------------------------------------------------------
extern "C" void kernel_launch(void* const* d_in, const int* in_sizes, int n_in,
                              void* d_out, int out_size, void* d_ws, size_t ws_size,
                              hipStream_t stream) {
    const float* x           = (const float*)d_in[0];
    const float* lvl_raw     = (const float*)d_in[1];
    const float* seas_raw    = (const float*)d_in[2];
    const float* seas_params = (const float*)d_in[3];
    const float* noise_in    = (const float*)d_in[4];
    const float* noise_lab   = (const float*)d_in[5];
    const float* Wx0         = (const float*)d_in[6];
    const float* Wh0         = (const float*)d_in[7];
    const float* b0v         = (const float*)d_in[8];
    const float* Wx1         = (const float*)d_in[9];
    const float* Wh1         = (const float*)d_in[10];
    const float* b1v         = (const float*)d_in[11];
    const float* tanhW       = (const float*)d_in[12];
    const float* tanhB       = (const float*)d_in[13];
    const float* linW        = (const float*)d_in[14];
    const float* linB        = (const float*)d_in[15];
    float* out = (float*)d_out;

    // workspace layout (floats; pw0/pw1/hs0 16B-aligned by construction)
    // total need ~38.2MB — verified available in round 3.
    float* wsf    = (float*)d_ws;
    float* levels = wsf;                                   // 1024
    float* wsv    = levels + T_LEN;                        // 1024
    float* sqT    = wsv + T_LEN;                           // 139944
    float* hfin   = sqT + WIN_SZ * N_WIN;                  // 106624
    float* tanhWT = hfin + N_WIN * H_SZ;                   // 16384
    uint4* pw0    = (uint4*)(tanhWT + H_SZ * H_SZ);        // 8192 uint4
    uint4* pw1    = pw0 + 8192;                            // 16384 uint4
    __bf16* hs0   = (__bf16*)(pw1 + 16384);                // 168*848*128 bf16

    hipLaunchKernelGGL(es_scan_kernel, dim3(1), dim3(256), 0, stream,
                       x, lvl_raw, seas_raw, seas_params, levels, wsv);
    hipLaunchKernelGGL(prep_weights, dim3(160), dim3(256), 0, stream,
                       Wh0, Wx1, Wh1, tanhW, pw0, pw1, tanhWT);
    hipLaunchKernelGGL(window_kernel, dim3(WIN_SZ + OUT_SZ), dim3(256), 0, stream,
                       x, levels, wsv, noise_in, noise_lab, sqT, out);
    hipLaunchKernelGGL(l0_kernel, dim3(NBLK), dim3(512), 0, stream,
                       sqT, Wx0, b0v, pw0, hs0);
    hipLaunchKernelGGL(l1_kernel, dim3(NBLK), dim3(512), 0, stream,
                       hs0, b1v, pw1, hfin);
    hipLaunchKernelGGL(head_kernel, dim3(N_WIN), dim3(128), 0, stream,
                       hfin, tanhWT, tanhB, linW, linB, out);
}

// Round 6
// 786.678 us; speedup vs baseline: 1.1646x; 1.1646x over previous
//
#include <hip/hip_runtime.h>
#include <math.h>

#define T_LEN   1024
#define S_SEAS  168
#define H_SZ    128
#define G_SZ    512   // 4*H
#define WIN_SZ  168
#define OUT_SZ  24
#define N_WIN   833
#define BB      16
#define NBLK    ((N_WIN + BB - 1) / BB)   // 53
#define NPAD    (NBLK * BB)               // 848

typedef __attribute__((ext_vector_type(8))) __bf16 bf16x8;
typedef __attribute__((ext_vector_type(4))) float  f32x4;

__device__ __forceinline__ float fsig(float x) {
    return __fdividef(1.0f, 1.0f + __expf(-x));
}
__device__ __forceinline__ float ftanh(float x) {
    return 1.0f - __fdividef(2.0f, __expf(2.0f * x) + 1.0f);
}

// LDS h-tile addressing: pitch 256B (128 bf16), XOR swizzle byte^=(row&7)<<4
// (m214 recipe). Verified rounds 2-5 (absmax 0.002).
__device__ __forceinline__ int hswz(int row, int colByte) {
    return row * 256 + (colByte ^ ((row & 7) << 4));
}

// ---------------------------------------------------------------------------
// Phase A: Holt-Winters ES scan (serial, software-pipelined).
// ---------------------------------------------------------------------------
__global__ void es_scan_kernel(const float* __restrict__ x,
                               const float* __restrict__ lvl_raw,
                               const float* __restrict__ seas_raw,
                               const float* __restrict__ seas_params,
                               float* __restrict__ levels,
                               float* __restrict__ wsv) {
    __shared__ float xl[T_LEN];
    __shared__ float buf[S_SEAS];
    const int t = threadIdx.x;
    for (int i = t; i < T_LEN; i += 256) xl[i] = x[i];
    for (int i = t; i < S_SEAS; i += 256) {
        const float w = expf(seas_params[i]);
        buf[i] = w;
        wsv[i] = w;
    }
    __syncthreads();
    if (t == 0) {
        const float a  = 1.0f / (1.0f + expf(-lvl_raw[0]));
        const float g  = 1.0f / (1.0f + expf(-seas_raw[0]));
        const float ca = 1.0f - a, cg = 1.0f - g;
        float level = __fdividef(xl[0], buf[0]);
        levels[0] = level;
        wsv[S_SEAS] = buf[0];   // ws_full[168] = w_init[0]

        float wq[8], tq[8];
#pragma unroll
        for (int k = 0; k < 8; ++k) {
            const int i = 1 + k;
            const float w = buf[i % S_SEAS];
            wq[k] = w;
            tq[k] = __fdividef(a * xl[i], w);
        }
        for (int i = 1; i < T_LEN; i += 8) {
#pragma unroll
            for (int s = 0; s < 8; ++s) {
                const int ii = i + s;
                if (ii >= T_LEN) break;
                const float w  = wq[s];
                const float nl = tq[s] + ca * level;      // critical chain: 1 FMA
                const float nw = cg * w + __fdividef(g * xl[ii], nl);
                levels[ii] = nl;
                buf[ii % S_SEAS] = nw;
                if (ii + S_SEAS < T_LEN) wsv[ii + S_SEAS] = nw;
                level = nl;
                const int i8 = ii + 8;
                if (i8 < T_LEN) {
                    const float w8 = buf[i8 % S_SEAS];
                    wq[s] = w8;
                    tq[s] = __fdividef(a * xl[i8], w8);
                }
            }
        }
    }
}

// ---------------------------------------------------------------------------
// Phase B: deseasonalized log inputs (time-major sq_inT [168][833]) + labels
// (directly into d_out) + level_var_loss scalar.
// ---------------------------------------------------------------------------
__global__ __launch_bounds__(256) void window_kernel(
    const float* __restrict__ x,
    const float* __restrict__ levels,
    const float* __restrict__ wsv,
    const float* __restrict__ noise_in,
    const float* __restrict__ noise_lab,
    float* __restrict__ sqT,
    float* __restrict__ outbuf) {
    const int p = blockIdx.x;   // 0..167: window pos; 168..191: label pos
    for (int nn = threadIdx.x; nn < N_WIN; nn += 256) {
        const float lev = levels[nn + WIN_SZ];
        if (p < WIN_SZ) {
            const int tt = nn + p;
            sqT[p * N_WIN + nn] =
                logf(x[tt] / (lev * wsv[tt])) + noise_in[nn * WIN_SZ + p];
        } else {
            const int o = p - WIN_SZ;
            const int tt = nn + WIN_SZ + o;
            outbuf[N_WIN * OUT_SZ + nn * OUT_SZ + o] =
                logf(x[tt] / (lev * wsv[tt])) + noise_lab[nn * OUT_SZ + o];
        }
    }
    if (blockIdx.x == 0 && threadIdx.x == 0)
        outbuf[2 * N_WIN * OUT_SZ] = 0.0f;   // level_var_loss
}

// ---------------------------------------------------------------------------
// Weight prep: pack Wh0 / [Wx1;Wh1] into per-lane bf16 MFMA B-fragments.
// B-frag layout (m92/m97): lane l holds col n=(l&15), 8 contiguous k at
// (l>>4)*8. Fragment f for wave w, gate ns, K-tile kt at pw[f*64+l].
// ---------------------------------------------------------------------------
__global__ __launch_bounds__(256) void prep_weights(
    const float* __restrict__ Wh0,
    const float* __restrict__ Wx1,
    const float* __restrict__ Wh1,
    const float* __restrict__ tanhW,
    uint4* __restrict__ pw0,
    uint4* __restrict__ pw1,
    float* __restrict__ tanhWT) {
    const int idx = blockIdx.x * 256 + threadIdx.x;
    auto bfr = [](float f) -> unsigned int {   // fp32 -> bf16 (RNE)
        union { float f; unsigned int u; } v; v.f = f;
        return ((v.u + 0x7FFFu + ((v.u >> 16) & 1u)) >> 16) & 0xFFFFu;
    };
    if (idx < 8192) {                       // pw0: Wh0, 128 frags (8w x 4ns x 4kt)
        const int l = idx & 63, f = idx >> 6;
        const int kt = f & 3, ns = (f >> 2) & 3, w = f >> 4;
        const int g = ns * 128 + w * 16 + (l & 15);
        const int kb = kt * 32 + (l >> 4) * 8;
        const float* s = Wh0 + g * H_SZ + kb;
        uint4 o;
        unsigned int* po = &o.x;
        for (int p = 0; p < 4; ++p) po[p] = bfr(s[2 * p]) | (bfr(s[2 * p + 1]) << 16);
        pw0[idx] = o;
    } else if (idx < 8192 + 16384) {        // pw1: [Wx1 (kt<4); Wh1 (kt>=4)], 256 frags
        const int j = idx - 8192;
        const int l = j & 63, f = j >> 6;
        const int kt = f & 7, ns = (f >> 3) & 3, w = f >> 5;
        const int g = ns * 128 + w * 16 + (l & 15);
        const float* srcm = (kt < 4) ? Wx1 : Wh1;
        const int kb = (kt & 3) * 32 + (l >> 4) * 8;
        const float* s = srcm + g * H_SZ + kb;
        uint4 o;
        unsigned int* po = &o.x;
        for (int p = 0; p < 4; ++p) po[p] = bfr(s[2 * p]) | (bfr(s[2 * p + 1]) << 16);
        pw1[j] = o;
    } else if (idx < 8192 + 16384 + 16384) {  // tanh_W transpose (fp32)
        const int j = idx - 8192 - 16384;
        const int m = j >> 7, k = j & 127;
        tanhWT[k * H_SZ + m] = tanhW[j];
    }
}

// ---------------------------------------------------------------------------
// Phase C0: layer-0 LSTM. Wh0 B-frags pinned in AGPRs (64/lane) via the
// "+a" empty-asm class constraint — zero per-step weight traffic. h0
// double-buffered bf16 in LDS (swizzled); c-state in 4 VGPRs.
// ---------------------------------------------------------------------------
__global__ __launch_bounds__(512, 2) void l0_kernel(
    const float* __restrict__ sqT,
    const float* __restrict__ Wx0,
    const float* __restrict__ b0v,
    const uint4* __restrict__ pw0,
    __bf16* __restrict__ hs0) {
    __shared__ __bf16 h0s[2][16 * 128];    // 8KB, swizzled, pitch 256B
    __shared__ float  xls[WIN_SZ][16];     // 10.75KB

    const int tid  = threadIdx.x;
    const int w    = tid >> 6;
    const int lane = tid & 63;
    const int cc   = lane & 15;
    const int kl   = lane >> 4;
    const int base = blockIdx.x * BB;

    for (int i = tid; i < WIN_SZ * BB; i += 512) {
        const int t = i >> 4, m = i & 15;
        const int nn = base + m;
        xls[t][m] = (nn < N_WIN) ? sqT[t * N_WIN + nn] : 0.0f;
    }
    for (int i = tid; i < 2 * 16 * 128; i += 512) (&h0s[0][0])[i] = (__bf16)0.0f;

    // load Wh0 frags once, then pin each in the AGPR class
    const bf16x8* p0 = (const bf16x8*)pw0;
    bf16x8 wB0[4][4];
#pragma unroll
    for (int ns = 0; ns < 4; ++ns)
#pragma unroll
        for (int kt = 0; kt < 4; ++kt)
            wB0[ns][kt] = p0[((w * 4 + ns) * 4 + kt) * 64 + lane];
#pragma unroll
    for (int ns = 0; ns < 4; ++ns)
#pragma unroll
        for (int kt = 0; kt < 4; ++kt)
            asm("" : "+a"(wB0[ns][kt]));   // force AGPR residency (one-time)

    float b0r[4], wx0r[4];
#pragma unroll
    for (int ns = 0; ns < 4; ++ns) {
        const int g = ns * 128 + w * 16 + cc;
        b0r[ns]  = b0v[g];
        wx0r[ns] = Wx0[g];
    }
    float c0r[4] = {0.f, 0.f, 0.f, 0.f};
    __syncthreads();

    char* const hb0 = (char*)&h0s[0][0];

    for (int t = 0; t < WIN_SZ; ++t) {
        const int rb = t & 1, wb = rb ^ 1;
        const float4 xt = *(const float4*)&xls[t][kl * 4];
        const float xa[4] = {xt.x, xt.y, xt.z, xt.w};
        f32x4 acc0, acc1, acc2, acc3;
#pragma unroll
        for (int r = 0; r < 4; ++r) {
            acc0[r] = b0r[0] + wx0r[0] * xa[r];
            acc1[r] = b0r[1] + wx0r[1] * xa[r];
            acc2[r] = b0r[2] + wx0r[2] * xa[r];
            acc3[r] = b0r[3] + wx0r[3] * xa[r];
        }
#pragma unroll
        for (int kt = 0; kt < 4; ++kt) {
            const bf16x8 a = *(const bf16x8*)(hb0 + rb * 4096 + hswz(cc, kt * 64 + kl * 16));
            acc0 = __builtin_amdgcn_mfma_f32_16x16x32_bf16(a, wB0[0][kt], acc0, 0, 0, 0);
            acc1 = __builtin_amdgcn_mfma_f32_16x16x32_bf16(a, wB0[1][kt], acc1, 0, 0, 0);
            acc2 = __builtin_amdgcn_mfma_f32_16x16x32_bf16(a, wB0[2][kt], acc2, 0, 0, 0);
            acc3 = __builtin_amdgcn_mfma_f32_16x16x32_bf16(a, wB0[3][kt], acc3, 0, 0, 0);
        }
#pragma unroll
        for (int r = 0; r < 4; ++r) {
            const float ig = fsig(acc0[r]);
            const float fg = fsig(acc1[r]);
            const float gg = ftanh(acc2[r]);
            const float og = fsig(acc3[r]);
            const float c  = fg * c0r[r] + ig * gg;
            c0r[r] = c;
            const __bf16 hb = (__bf16)(og * ftanh(c));
            const int row = kl * 4 + r;
            *(__bf16*)(hb0 + wb * 4096 + hswz(row, (w * 16 + cc) * 2)) = hb;
            hs0[t * (NPAD * H_SZ) + (base + row) * H_SZ + w * 16 + cc] = hb;
        }
        __syncthreads();
    }
}

// ---------------------------------------------------------------------------
// Phase C1: layer-1 LSTM. Wx1+Wh1 B-frags pinned in AGPRs (128/lane).
// A-operand of the Wx1 term streams from hs0 with named-register 1-step
// prefetch; h1 double-buffered in LDS.
// ---------------------------------------------------------------------------
__global__ __launch_bounds__(512, 2) void l1_kernel(
    const __bf16* __restrict__ hs0,
    const float* __restrict__ b1v,
    const uint4* __restrict__ pw1,
    float* __restrict__ hfin) {
    __shared__ __bf16 h1s[2][16 * 128];    // 8KB, swizzled

    const int tid  = threadIdx.x;
    const int w    = tid >> 6;
    const int lane = tid & 63;
    const int cc   = lane & 15;
    const int kl   = lane >> 4;
    const int base = blockIdx.x * BB;

    for (int i = tid; i < 2 * 16 * 128; i += 512) (&h1s[0][0])[i] = (__bf16)0.0f;

    // load Wx1 (kt<4) and Wh1 (kt>=4) frags once, pin in AGPRs
    const bf16x8* p1 = (const bf16x8*)pw1;
    bf16x8 wX[4][4], wH[4][4];
#pragma unroll
    for (int ns = 0; ns < 4; ++ns)
#pragma unroll
        for (int kt = 0; kt < 4; ++kt) {
            wX[ns][kt] = p1[((w * 4 + ns) * 8 + kt) * 64 + lane];
            wH[ns][kt] = p1[((w * 4 + ns) * 8 + kt + 4) * 64 + lane];
        }
#pragma unroll
    for (int ns = 0; ns < 4; ++ns)
#pragma unroll
        for (int kt = 0; kt < 4; ++kt) {
            asm("" : "+a"(wX[ns][kt]));
            asm("" : "+a"(wH[ns][kt]));
        }

    float b1r[4];
#pragma unroll
    for (int ns = 0; ns < 4; ++ns) b1r[ns] = b1v[ns * 128 + w * 16 + cc];
    float c1r[4] = {0.f, 0.f, 0.f, 0.f};

    // A-frag prefetch for t=0 (named regs)
    const int arow = (base + cc) * H_SZ + kl * 8;
    bf16x8 f0 = *(const bf16x8*)&hs0[arow + 0];
    bf16x8 f1 = *(const bf16x8*)&hs0[arow + 32];
    bf16x8 f2 = *(const bf16x8*)&hs0[arow + 64];
    bf16x8 f3 = *(const bf16x8*)&hs0[arow + 96];
    __syncthreads();

    char* const hb1 = (char*)&h1s[0][0];

    for (int t = 0; t < WIN_SZ; ++t) {
        const int rb = t & 1, wb = rb ^ 1;

        bf16x8 g0 = f0, g1 = f1, g2 = f2, g3 = f3;
        if (t < WIN_SZ - 1) {
            const __bf16* p = hs0 + (t + 1) * (NPAD * H_SZ) + arow;
            g0 = *(const bf16x8*)(p);
            g1 = *(const bf16x8*)(p + 32);
            g2 = *(const bf16x8*)(p + 64);
            g3 = *(const bf16x8*)(p + 96);
        }

        f32x4 acc0 = {b1r[0], b1r[0], b1r[0], b1r[0]};
        f32x4 acc1 = {b1r[1], b1r[1], b1r[1], b1r[1]};
        f32x4 acc2 = {b1r[2], b1r[2], b1r[2], b1r[2]};
        f32x4 acc3 = {b1r[3], b1r[3], b1r[3], b1r[3]};

        // Wx1 term: A = prefetched hs0 frags, B in AGPRs
        acc0 = __builtin_amdgcn_mfma_f32_16x16x32_bf16(f0, wX[0][0], acc0, 0, 0, 0);
        acc1 = __builtin_amdgcn_mfma_f32_16x16x32_bf16(f0, wX[1][0], acc1, 0, 0, 0);
        acc2 = __builtin_amdgcn_mfma_f32_16x16x32_bf16(f0, wX[2][0], acc2, 0, 0, 0);
        acc3 = __builtin_amdgcn_mfma_f32_16x16x32_bf16(f0, wX[3][0], acc3, 0, 0, 0);
        acc0 = __builtin_amdgcn_mfma_f32_16x16x32_bf16(f1, wX[0][1], acc0, 0, 0, 0);
        acc1 = __builtin_amdgcn_mfma_f32_16x16x32_bf16(f1, wX[1][1], acc1, 0, 0, 0);
        acc2 = __builtin_amdgcn_mfma_f32_16x16x32_bf16(f1, wX[2][1], acc2, 0, 0, 0);
        acc3 = __builtin_amdgcn_mfma_f32_16x16x32_bf16(f1, wX[3][1], acc3, 0, 0, 0);
        acc0 = __builtin_amdgcn_mfma_f32_16x16x32_bf16(f2, wX[0][2], acc0, 0, 0, 0);
        acc1 = __builtin_amdgcn_mfma_f32_16x16x32_bf16(f2, wX[1][2], acc1, 0, 0, 0);
        acc2 = __builtin_amdgcn_mfma_f32_16x16x32_bf16(f2, wX[2][2], acc2, 0, 0, 0);
        acc3 = __builtin_amdgcn_mfma_f32_16x16x32_bf16(f2, wX[3][2], acc3, 0, 0, 0);
        acc0 = __builtin_amdgcn_mfma_f32_16x16x32_bf16(f3, wX[0][3], acc0, 0, 0, 0);
        acc1 = __builtin_amdgcn_mfma_f32_16x16x32_bf16(f3, wX[1][3], acc1, 0, 0, 0);
        acc2 = __builtin_amdgcn_mfma_f32_16x16x32_bf16(f3, wX[2][3], acc2, 0, 0, 0);
        acc3 = __builtin_amdgcn_mfma_f32_16x16x32_bf16(f3, wX[3][3], acc3, 0, 0, 0);

        // Wh1 term: A = h1_prev from LDS, B in AGPRs
#pragma unroll
        for (int kt = 0; kt < 4; ++kt) {
            const bf16x8 a = *(const bf16x8*)(hb1 + rb * 4096 + hswz(cc, kt * 64 + kl * 16));
            acc0 = __builtin_amdgcn_mfma_f32_16x16x32_bf16(a, wH[0][kt], acc0, 0, 0, 0);
            acc1 = __builtin_amdgcn_mfma_f32_16x16x32_bf16(a, wH[1][kt], acc1, 0, 0, 0);
            acc2 = __builtin_amdgcn_mfma_f32_16x16x32_bf16(a, wH[2][kt], acc2, 0, 0, 0);
            acc3 = __builtin_amdgcn_mfma_f32_16x16x32_bf16(a, wH[3][kt], acc3, 0, 0, 0);
        }

#pragma unroll
        for (int r = 0; r < 4; ++r) {
            const float ig = fsig(acc0[r]);
            const float fg = fsig(acc1[r]);
            const float gg = ftanh(acc2[r]);
            const float og = fsig(acc3[r]);
            const float c  = fg * c1r[r] + ig * gg;
            c1r[r] = c;
            const float hv = og * ftanh(c);
            const int row = kl * 4 + r;
            if (t < WIN_SZ - 1) {
                *(__bf16*)(hb1 + wb * 4096 + hswz(row, (w * 16 + cc) * 2)) = (__bf16)hv;
            } else {
                const int nn = base + row;
                if (nn < N_WIN) hfin[nn * H_SZ + w * 16 + cc] = hv;
            }
        }
        __syncthreads();
        f0 = g0; f1 = g1; f2 = g2; f3 = g3;
    }
}

// ---------------------------------------------------------------------------
// Phase D: head — feat = tanh(h @ tanh_W^T + tanh_b); out = feat @ lin_W^T + lin_b
// ---------------------------------------------------------------------------
__global__ __launch_bounds__(128) void head_kernel(
    const float* __restrict__ hfin,
    const float* __restrict__ tanhWT,
    const float* __restrict__ tanhB,
    const float* __restrict__ linW,
    const float* __restrict__ linB,
    float* __restrict__ out) {
    __shared__ float hl[H_SZ];
    __shared__ float fl[H_SZ];
    const int nn = blockIdx.x;
    const int m = threadIdx.x;
    hl[m] = hfin[nn * H_SZ + m];
    __syncthreads();
    float acc = tanhB[m];
    for (int k = 0; k < H_SZ; ++k) acc += hl[k] * tanhWT[k * H_SZ + m];
    fl[m] = tanhf(acc);
    __syncthreads();
    if (m < OUT_SZ) {
        float a = linB[m];
        for (int k = 0; k < H_SZ; ++k) a += fl[k] * linW[m * H_SZ + k];
        out[nn * OUT_SZ + m] = a;
    }
}

// ---------------------------------------------------------------------------
extern "C" void kernel_launch(void* const* d_in, const int* in_sizes, int n_in,
                              void* d_out, int out_size, void* d_ws, size_t ws_size,
                              hipStream_t stream) {
    const float* x           = (const float*)d_in[0];
    const float* lvl_raw     = (const float*)d_in[1];
    const float* seas_raw    = (const float*)d_in[2];
    const float* seas_params = (const float*)d_in[3];
    const float* noise_in    = (const float*)d_in[4];
    const float* noise_lab   = (const float*)d_in[5];
    const float* Wx0         = (const float*)d_in[6];
    const float* Wh0         = (const float*)d_in[7];
    const float* b0v         = (const float*)d_in[8];
    const float* Wx1         = (const float*)d_in[9];
    const float* Wh1         = (const float*)d_in[10];
    const float* b1v         = (const float*)d_in[11];
    const float* tanhW       = (const float*)d_in[12];
    const float* tanhB       = (const float*)d_in[13];
    const float* linW        = (const float*)d_in[14];
    const float* linB        = (const float*)d_in[15];
    float* out = (float*)d_out;

    // workspace layout (floats; pw0/pw1/hs0 16B-aligned by construction)
    float* wsf    = (float*)d_ws;
    float* levels = wsf;                                   // 1024
    float* wsv    = levels + T_LEN;                        // 1024
    float* sqT    = wsv + T_LEN;                           // 139944
    float* hfin   = sqT + WIN_SZ * N_WIN;                  // 106624
    float* tanhWT = hfin + N_WIN * H_SZ;                   // 16384
    uint4* pw0    = (uint4*)(tanhWT + H_SZ * H_SZ);        // 8192 uint4
    uint4* pw1    = pw0 + 8192;                            // 16384 uint4
    __bf16* hs0   = (__bf16*)(pw1 + 16384);                // 168*848*128 bf16

    hipLaunchKernelGGL(es_scan_kernel, dim3(1), dim3(256), 0, stream,
                       x, lvl_raw, seas_raw, seas_params, levels, wsv);
    hipLaunchKernelGGL(prep_weights, dim3(160), dim3(256), 0, stream,
                       Wh0, Wx1, Wh1, tanhW, pw0, pw1, tanhWT);
    hipLaunchKernelGGL(window_kernel, dim3(WIN_SZ + OUT_SZ), dim3(256), 0, stream,
                       x, levels, wsv, noise_in, noise_lab, sqT, out);
    hipLaunchKernelGGL(l0_kernel, dim3(NBLK), dim3(512), 0, stream,
                       sqT, Wx0, b0v, pw0, hs0);
    hipLaunchKernelGGL(l1_kernel, dim3(NBLK), dim3(512), 0, stream,
                       hs0, b1v, pw1, hfin);
    hipLaunchKernelGGL(head_kernel, dim3(N_WIN), dim3(128), 0, stream,
                       hfin, tanhWT, tanhB, linW, linB, out);
}